// Round 1
// 874.857 us; speedup vs baseline: 1.2966x; 1.2966x over previous
//
#include <hip/hip_runtime.h>
#include <math.h>

// AlignmentLayer: B=4, C=2048, H=W=64 (P=4096), HID=256
// R1 polish: (a) out GEMM rewritten as 256x256-tile 8-phase pipelined kernel
//            (T2 swizzle + T3/T4 counted-vmcnt phases + T5 setprio),
//            (b) all stages batched over blockIdx.z -> 7 launches (needs 481MB ws,
//            falls back to legacy per-batch path otherwise).
// Schedule derivation (iter i, tiles t=2i,t+1; dbuf = tile&1; phases p1..p8):
//   consume: p1-p4 tile t (dbuf0), p5-p8 tile t+1 (dbuf1); quadrants (mh,nh)
//   stage:   p1:Alo(t+1) p2:Ahi(t+1) p3:Blo(t+2) p4:Bhi(t+2)
//            p5:Alo(t+2) p6:Ahi(t+2) p7:Blo(t+3) p8:Bhi(t+3)
//   waits:   vmcnt(4) end-p4 (guarantees t+1 halves), vmcnt(4) end-p8 (t+2);
//            every overwrite >=1 phase after last read of that half.

#define BATCH 4
#define CH    2048
#define PP    4096
#define DD    256

typedef __bf16    bf16x8 __attribute__((ext_vector_type(8)));
typedef _Float16  f16x8  __attribute__((ext_vector_type(8)));
typedef _Float16  f16x4  __attribute__((ext_vector_type(4)));
typedef float     f32x4  __attribute__((ext_vector_type(4)));

__device__ __forceinline__ unsigned short f2bf(float f) {
  unsigned int u = __float_as_uint(f);
  unsigned int r = u + 0x7fffu + ((u >> 16) & 1u);   // RNE
  return (unsigned short)(r >> 16);
}

#define GLL(src, dst) \
  __builtin_amdgcn_global_load_lds( \
      (const __attribute__((address_space(1))) unsigned int*)(uintptr_t)(src), \
      (__attribute__((address_space(3))) unsigned int*)(uintptr_t)(dst), 16, 0, 0)

// ---------------- prep_w: W fp32 [o][c] -> fp16 ----------------
__global__ __launch_bounds__(256) void prep_w(
    const float* __restrict__ W, _Float16* __restrict__ Wf) {
  int i = blockIdx.x * 256 + threadIdx.x;          // float4 units, 131072
  float4 v = ((const float4*)W)[i];
  f16x4 h = {(_Float16)v.x, (_Float16)v.y, (_Float16)v.z, (_Float16)v.w};
  ((f16x4*)Wf)[i] = h;
}

// ---------------- tsplit8: X [c][p] fp32 -> Xt [p][c] fp16, batched ----------------
// grid (PP/64, CH/64, NZ), block 256. z: tensor index, b=z>>1, (z&1)? prompt:query.
__global__ __launch_bounds__(256) void tsplit8(
    const float* __restrict__ Xq, const float* __restrict__ Xp,
    _Float16* __restrict__ Xt8) {
  const int z = blockIdx.z;
  const float* __restrict__ X =
      ((z & 1) ? Xp : Xq) + (size_t)(z >> 1) * CH * PP;
  _Float16* __restrict__ Xt = Xt8 + (size_t)z * CH * PP;

  __shared__ float Ls[64 * 65];
  const int tid = threadIdx.x;
  const int pBase = blockIdx.x * 64, cBase = blockIdx.y * 64;
#pragma unroll
  for (int i = 0; i < 4; ++i) {
    int e = tid + i * 256;               // 0..1023 float4 units
    int c = e >> 4, p4 = e & 15;
    float4 v = *(const float4*)&X[(size_t)(cBase + c) * PP + pBase + p4 * 4];
    Ls[c * 65 + p4 * 4 + 0] = v.x; Ls[c * 65 + p4 * 4 + 1] = v.y;
    Ls[c * 65 + p4 * 4 + 2] = v.z; Ls[c * 65 + p4 * 4 + 3] = v.w;
  }
  __syncthreads();
#pragma unroll
  for (int j = 0; j < 4; ++j) {
    int p = (tid >> 4) + j * 16;         // 0..63
    int c4 = (tid & 15) * 4;
    f16x4 h = {(_Float16)Ls[(c4 + 0) * 65 + p], (_Float16)Ls[(c4 + 1) * 65 + p],
               (_Float16)Ls[(c4 + 2) * 65 + p], (_Float16)Ls[(c4 + 3) * 65 + p]};
    *(f16x4*)&Xt[(size_t)(pBase + p) * CH + cBase + c4] = h;
  }
}

// ---------------- proj8: Y = Xt Wf^T + b -> bf16 hi/lo, batched ----------------
// grid (PP/64, DD/64, NZ). z&1 ? (Kh,Kl) : (Qh,Ql); batch b=z>>1.
__global__ __launch_bounds__(256) void proj8(
    const _Float16* __restrict__ Xt8, const _Float16* __restrict__ Wf,
    const float* __restrict__ bias,
    unsigned short* __restrict__ Qh, unsigned short* __restrict__ Ql,
    unsigned short* __restrict__ Kh, unsigned short* __restrict__ Kl) {
  const int z = blockIdx.z;
  const _Float16* __restrict__ Xt = Xt8 + (size_t)z * CH * PP;
  unsigned short* __restrict__ Yh =
      ((z & 1) ? Kh : Qh) + (size_t)(z >> 1) * PP * DD;
  unsigned short* __restrict__ Yl =
      ((z & 1) ? Kl : Ql) + (size_t)(z >> 1) * PP * DD;

  const int pBase = blockIdx.x * 64;
  const int oBase = blockIdx.y * 64;
  const int tid  = threadIdx.x;
  const int wave = tid >> 6;
  const int lane = tid & 63;
  const int wm = wave & 1, wn = wave >> 1;
  const int row16 = lane & 15, quad = lane >> 4, koff = quad * 8;

  __shared__ __align__(16) _Float16 As0[64 * 32], As1[64 * 32];
  __shared__ __align__(16) _Float16 Bs0[64 * 32], Bs1[64 * 32];

  const int sRow = lane >> 2;            // 0..15
  const int sKc  = (lane & 3) * 8;       // fp16 elems, 16B chunks

  f32x4 acc[2][2];
#pragma unroll
  for (int i = 0; i < 2; ++i)
#pragma unroll
    for (int j = 0; j < 2; ++j) acc[i][j] = (f32x4){0.f, 0.f, 0.f, 0.f};

  for (int c0 = 0; c0 < CH; c0 += 64) {
    const int row = wave * 16 + sRow;    // wave-uniform base + lane scatter
    GLL(&Xt[(size_t)(pBase + row) * CH + c0 + sKc],      &As0[(wave * 16) * 32]);
    GLL(&Xt[(size_t)(pBase + row) * CH + c0 + 32 + sKc], &As1[(wave * 16) * 32]);
    GLL(&Wf[(size_t)(oBase + row) * CH + c0 + sKc],      &Bs0[(wave * 16) * 32]);
    GLL(&Wf[(size_t)(oBase + row) * CH + c0 + 32 + sKc], &Bs1[(wave * 16) * 32]);
    __syncthreads();
#pragma unroll
    for (int s = 0; s < 2; ++s) {
      const _Float16* Ap = s ? As1 : As0;
      const _Float16* Bp = s ? Bs1 : Bs0;
      f16x8 af[2], bf[2];
#pragma unroll
      for (int i = 0; i < 2; ++i)
        af[i] = *(const f16x8*)&Ap[(wm * 32 + i * 16 + row16) * 32 + koff];
#pragma unroll
      for (int j = 0; j < 2; ++j)
        bf[j] = *(const f16x8*)&Bp[(wn * 32 + j * 16 + row16) * 32 + koff];
#pragma unroll
      for (int i = 0; i < 2; ++i)
#pragma unroll
        for (int j = 0; j < 2; ++j)
          acc[i][j] = __builtin_amdgcn_mfma_f32_16x16x32_f16(
              af[i], bf[j], acc[i][j], 0, 0, 0);
    }
    __syncthreads();
  }

#pragma unroll
  for (int i = 0; i < 2; ++i)
#pragma unroll
    for (int j = 0; j < 2; ++j) {
      const int ocol = oBase + wn * 32 + j * 16 + row16;
      const float bv = bias[ocol];
#pragma unroll
      for (int r = 0; r < 4; ++r) {
        const int prow = pBase + wm * 32 + i * 16 + quad * 4 + r;
        float y = acc[i][j][r] + bv;
        unsigned short h = f2bf(y);
        float hf = __uint_as_float((unsigned int)h << 16);
        unsigned short l = f2bf(y - hf);
        Yh[(size_t)prow * DD + ocol] = h;
        Yl[(size_t)prow * DD + ocol] = l;
      }
    }
}

// ---------------- scores8: S = (Qh+Ql)(Kh+Kl)^T, 3-term bf16, batched ----------------
// grid (PP/128, PP/128, NB); tile 128x128, BK=32, K=256.
__global__ __launch_bounds__(256) void scores8(
    const unsigned short* __restrict__ Qh_, const unsigned short* __restrict__ Ql_,
    const unsigned short* __restrict__ Kh_, const unsigned short* __restrict__ Kl_,
    float* __restrict__ S_) {
  const size_t z = blockIdx.z;
  const unsigned short* __restrict__ Qh = Qh_ + z * (size_t)PP * DD;
  const unsigned short* __restrict__ Ql = Ql_ + z * (size_t)PP * DD;
  const unsigned short* __restrict__ Kh = Kh_ + z * (size_t)PP * DD;
  const unsigned short* __restrict__ Kl = Kl_ + z * (size_t)PP * DD;
  float* __restrict__ S = S_ + z * (size_t)PP * PP;

  const int kBase = blockIdx.x * 128;
  const int pBase = blockIdx.y * 128;
  const int tid  = threadIdx.x;
  const int wave = tid >> 6;
  const int lane = tid & 63;
  const int wm = wave & 1, wn = wave >> 1;
  const int row16 = lane & 15, quad = lane >> 4, koff = quad * 8;

  __shared__ __align__(16) unsigned short Ah[128 * 32], Al[128 * 32];
  __shared__ __align__(16) unsigned short Bh[128 * 32], Bl[128 * 32];

  const int sRow = lane >> 2;
  const int sKc  = (lane & 3) * 8;

  f32x4 acc[4][4];
#pragma unroll
  for (int i = 0; i < 4; ++i)
#pragma unroll
    for (int j = 0; j < 4; ++j) acc[i][j] = (f32x4){0.f, 0.f, 0.f, 0.f};

  for (int d0 = 0; d0 < DD; d0 += 32) {
#pragma unroll
    for (int t = 0; t < 2; ++t) {
      const int rg = wave * 32 + t * 16;
      const int row = rg + sRow;
      GLL(&Qh[(size_t)(pBase + row) * DD + d0 + sKc], &Ah[rg * 32]);
      GLL(&Ql[(size_t)(pBase + row) * DD + d0 + sKc], &Al[rg * 32]);
      GLL(&Kh[(size_t)(kBase + row) * DD + d0 + sKc], &Bh[rg * 32]);
      GLL(&Kl[(size_t)(kBase + row) * DD + d0 + sKc], &Bl[rg * 32]);
    }
    __syncthreads();
    bf16x8 ah[4], al[4], bh[4], bl[4];
#pragma unroll
    for (int i = 0; i < 4; ++i) {
      ah[i] = *(const bf16x8*)&Ah[(wm * 64 + i * 16 + row16) * 32 + koff];
      al[i] = *(const bf16x8*)&Al[(wm * 64 + i * 16 + row16) * 32 + koff];
    }
#pragma unroll
    for (int j = 0; j < 4; ++j) {
      bh[j] = *(const bf16x8*)&Bh[(wn * 64 + j * 16 + row16) * 32 + koff];
      bl[j] = *(const bf16x8*)&Bl[(wn * 64 + j * 16 + row16) * 32 + koff];
    }
#pragma unroll
    for (int i = 0; i < 4; ++i)
#pragma unroll
      for (int j = 0; j < 4; ++j) {
        acc[i][j] = __builtin_amdgcn_mfma_f32_16x16x32_bf16(ah[i], bh[j], acc[i][j], 0, 0, 0);
        acc[i][j] = __builtin_amdgcn_mfma_f32_16x16x32_bf16(ah[i], bl[j], acc[i][j], 0, 0, 0);
        acc[i][j] = __builtin_amdgcn_mfma_f32_16x16x32_bf16(al[i], bh[j], acc[i][j], 0, 0, 0);
      }
    __syncthreads();
  }

#pragma unroll
  for (int i = 0; i < 4; ++i)
#pragma unroll
    for (int j = 0; j < 4; ++j) {
      const int kcol = kBase + wn * 64 + j * 16 + row16;
#pragma unroll
      for (int r = 0; r < 4; ++r) {
        const int prow = pBase + wm * 64 + i * 16 + quad * 4 + r;
        S[(size_t)prow * PP + kcol] = acc[i][j][r];
      }
    }
}

// ---------------- softmax rows; writes bf16 in place, batched ----------------
// grid (PP, NB)
__global__ __launch_bounds__(256) void softmax8(float* __restrict__ S_) {
  float* __restrict__ Sb = S_ + (size_t)blockIdx.y * PP * PP;
  unsigned short* __restrict__ Ab = (unsigned short*)Sb;
  const size_t p = blockIdx.x;
  float* row = Sb + p * PP;
  const int tid = threadIdx.x;
  float4 v[4];
#pragma unroll
  for (int i = 0; i < 4; ++i)
    v[i] = *(const float4*)&row[(i * 256 + tid) * 4];
  float m = -1e30f;
#pragma unroll
  for (int i = 0; i < 4; ++i)
    m = fmaxf(m, fmaxf(fmaxf(v[i].x, v[i].y), fmaxf(v[i].z, v[i].w)));
#pragma unroll
  for (int off = 32; off > 0; off >>= 1)
    m = fmaxf(m, __shfl_xor(m, off));
  __shared__ float red[4];
  const int lane = tid & 63, wv = tid >> 6;
  if (lane == 0) red[wv] = m;
  __syncthreads();
  m = fmaxf(fmaxf(red[0], red[1]), fmaxf(red[2], red[3]));
  __syncthreads();
  float s = 0.f;
#pragma unroll
  for (int i = 0; i < 4; ++i) {
    v[i].x = __expf(v[i].x - m);
    v[i].y = __expf(v[i].y - m);
    v[i].z = __expf(v[i].z - m);
    v[i].w = __expf(v[i].w - m);
    s += v[i].x + v[i].y + v[i].z + v[i].w;
  }
#pragma unroll
  for (int off = 32; off > 0; off >>= 1)
    s += __shfl_xor(s, off);
  if (lane == 0) red[wv] = s;
  __syncthreads();
  s = red[0] + red[1] + red[2] + red[3];
  const float inv = 1.f / s;
  unsigned short* orow = Ab + p * 8192;
#pragma unroll
  for (int i = 0; i < 4; ++i) {
    ushort4 o;
    o.x = f2bf(v[i].x * inv); o.y = f2bf(v[i].y * inv);
    o.z = f2bf(v[i].z * inv); o.w = f2bf(v[i].w * inv);
    *(ushort4*)&orow[(i * 256 + tid) * 4] = o;
  }
}

// ---------------- cvt: fp32 -> bf16 ----------------
__global__ __launch_bounds__(256) void cvt_bf16(
    const float* __restrict__ X, unsigned short* __restrict__ Y, int n4) {
  int i = blockIdx.x * blockDim.x + threadIdx.x;
  if (i < n4) {
    float4 v = ((const float4*)X)[i];
    ushort4 o;
    o.x = f2bf(v.x); o.y = f2bf(v.y); o.z = f2bf(v.z); o.w = f2bf(v.w);
    ((ushort4*)Y)[i] = o;
  }
}

// ---------------- out8: Out = V A^T -- 256x256 tile, 8-phase pipeline ----------------
// V: [CH][PP] bf16 (M=CH side). A: [PP][8192-stride] bf16 (N=PP side, bf16 rows
// aliased over fp32 S). Out: [CH][PP] fp32. K = PP = 4096, KT = 64 tiles of BK=64.
// 512 thr = 8 waves (2M x 4N); per-wave 128x64 out; acc[8][4] f32x4.
// LDS 128KB: A regions d*32768+h*16384, B at +65536. Swizzle: byte ^= (row&7)<<4
// on both write (pre-swizzled global src) and read.

#define AOFF(d, h) ((d) * 32768 + (h) * 16384)
#define BOFF(d, h) (65536 + (d) * 32768 + (h) * 16384)

#define PH_READ_A(d, mh) do {                                                  \
  _Pragma("unroll")                                                            \
  for (int m_ = 0; m_ < 4; ++m_) {                                             \
    const int ro_ = AOFF(d, wm) + ((mh) * 64 + m_ * 16 + row16) * 128;         \
    aR[m_][0] = *(const bf16x8*)(Lds + ro_ + cx0);                             \
    aR[m_][1] = *(const bf16x8*)(Lds + ro_ + cx1);                             \
  } } while (0)

#define PH_READ_B(d, nh, breg) do {                                            \
  _Pragma("unroll")                                                            \
  for (int n_ = 0; n_ < 2; ++n_) {                                             \
    const int ro_ = BOFF(d, wnh) + (wnl * 64 + (nh) * 32 + n_ * 16 + row16) * 128; \
    breg[n_][0] = *(const bf16x8*)(Lds + ro_ + cx0);                           \
    breg[n_][1] = *(const bf16x8*)(Lds + ro_ + cx1);                           \
  } } while (0)

#define PH_MFMA(mh, nh, breg) do {                                             \
  __builtin_amdgcn_s_setprio(1);                                               \
  _Pragma("unroll")                                                            \
  for (int m_ = 0; m_ < 4; ++m_)                                               \
  _Pragma("unroll")                                                            \
  for (int n_ = 0; n_ < 2; ++n_) {                                             \
    f32x4 a_ = acc[(mh) * 4 + m_][(nh) * 2 + n_];                              \
    a_ = __builtin_amdgcn_mfma_f32_16x16x32_bf16(aR[m_][0], breg[n_][0], a_, 0, 0, 0); \
    a_ = __builtin_amdgcn_mfma_f32_16x16x32_bf16(aR[m_][1], breg[n_][1], a_, 0, 0, 0); \
    acc[(mh) * 4 + m_][(nh) * 2 + n_] = a_;                                    \
  }                                                                            \
  __builtin_amdgcn_s_setprio(0); } while (0)

#define BAR_MID() do {                                                         \
  __builtin_amdgcn_sched_barrier(0);                                           \
  __builtin_amdgcn_s_barrier();                                                \
  asm volatile("s_waitcnt lgkmcnt(0)" ::: "memory");                           \
  __builtin_amdgcn_sched_barrier(0); } while (0)

#define BAR_END() __builtin_amdgcn_s_barrier()

__global__ __launch_bounds__(512, 2) void out8(
    const unsigned short* __restrict__ V_,
    const unsigned short* __restrict__ A_,
    float* __restrict__ O_) {
  const size_t z = blockIdx.z;
  const unsigned short* __restrict__ Vb = V_ + z * (size_t)CH * PP;
  const unsigned short* __restrict__ Ab = A_ + z * (size_t)PP * 8192;
  float* __restrict__ Ob = O_ + z * (size_t)CH * PP;

  const int pBase = blockIdx.x * 256;   // N (p columns)
  const int cBase = blockIdx.y * 256;   // M (channels)
  const int tid = threadIdx.x;
  const int wave = tid >> 6, lane = tid & 63;
  const int wm = wave >> 2;             // 0..1 (M)
  const int wn = wave & 3;              // 0..3 (N)
  const int wnh = wn >> 1, wnl = wn & 1;
  const int row16 = lane & 15, quad = lane >> 4;

  __shared__ __align__(16) char Lds[131072];

  // swizzled ds_read chunk offsets (bytes): chunk = (ks*4+quad) ^ (row&7)
  const int swz = (row16 & 7) << 4;
  const int cx0 = ((quad) << 4) ^ swz;
  const int cx1 = ((4 + quad) << 4) ^ swz;

  // staging constants: issue e covers rows (wave*2+e)*8 + (lane>>3),
  // source col chunk pre-swizzled: (lane&7) ^ (lane>>3)
  const int stRow0 = (wave * 2 + 0) * 8 + (lane >> 3);
  const int stRow1 = (wave * 2 + 1) * 8 + (lane >> 3);
  const int stCol  = (((lane & 7) ^ (lane >> 3)) << 4);
  char* ldsSt0 = Lds + (wave * 2 + 0) * 1024;
  char* ldsSt1 = Lds + (wave * 2 + 1) * 1024;

  const size_t VLDG = (size_t)PP * 2;      // 8192 B
  const size_t ALDG = (size_t)8192 * 2;    // 16384 B

  auto STG = [&](int ldsOff, const void* gbase, size_t ldgB, int rowBase, int gkB) {
    const char* g0 = (const char*)gbase + (size_t)(rowBase + stRow0) * ldgB + gkB + stCol;
    const char* g1 = (const char*)gbase + (size_t)(rowBase + stRow1) * ldgB + gkB + stCol;
    GLL(g0, ldsSt0 + ldsOff);
    GLL(g1, ldsSt1 + ldsOff);
  };

  f32x4 acc[8][4];
#pragma unroll
  for (int i = 0; i < 8; ++i)
#pragma unroll
    for (int j = 0; j < 4; ++j) acc[i][j] = (f32x4){0.f, 0.f, 0.f, 0.f};

  bf16x8 aR[4][2], bLo[2][2], bHi[2][2];

  // ---- prologue: tile0 (B then A) into dbuf0, tile1 B-halves into dbuf1 ----
  STG(BOFF(0, 0), Ab, ALDG, pBase + 0,   0);
  STG(BOFF(0, 1), Ab, ALDG, pBase + 128, 0);
  STG(AOFF(0, 0), Vb, VLDG, cBase + 0,   0);
  STG(AOFF(0, 1), Vb, VLDG, cBase + 128, 0);
  STG(BOFF(1, 0), Ab, ALDG, pBase + 0,   128);
  STG(BOFF(1, 1), Ab, ALDG, pBase + 128, 128);
  asm volatile("s_waitcnt vmcnt(4)" ::: "memory");
  __builtin_amdgcn_s_barrier();

  // ---- main loop: iters 0..30 (tiles 0..61 consumed), peel iter 31 ----
#pragma unroll 1
  for (int i = 0; i < 31; ++i) {
    const int t = 2 * i;
    const int gk1 = (t + 1) * 128, gk2 = (t + 2) * 128, gk3 = (t + 3) * 128;
    // p1: (0,0) on dbuf0 | stage A-lo(t+1) -> A d1 h0
    PH_READ_A(0, 0); PH_READ_B(0, 0, bLo);
    STG(AOFF(1, 0), Vb, VLDG, cBase + 0, gk1);
    BAR_MID(); PH_MFMA(0, 0, bLo); BAR_END();
    // p2: (0,1) | stage A-hi(t+1)
    PH_READ_B(0, 1, bHi);
    STG(AOFF(1, 1), Vb, VLDG, cBase + 128, gk1);
    BAR_MID(); PH_MFMA(0, 1, bHi); BAR_END();
    // p3: (1,0) | stage B-lo(t+2)
    PH_READ_A(0, 1);
    STG(BOFF(0, 0), Ab, ALDG, pBase + 0, gk2);
    BAR_MID(); PH_MFMA(1, 0, bLo); BAR_END();
    // p4: (1,1) | stage B-hi(t+2) | vmcnt(4): t+1 ready
    STG(BOFF(0, 1), Ab, ALDG, pBase + 128, gk2);
    BAR_MID(); PH_MFMA(1, 1, bHi);
    asm volatile("s_waitcnt vmcnt(4)" ::: "memory");
    BAR_END();
    // p5: (0,0) on dbuf1 | stage A-lo(t+2)
    PH_READ_A(1, 0); PH_READ_B(1, 0, bLo);
    STG(AOFF(0, 0), Vb, VLDG, cBase + 0, gk2);
    BAR_MID(); PH_MFMA(0, 0, bLo); BAR_END();
    // p6: (0,1) | stage A-hi(t+2)
    PH_READ_B(1, 1, bHi);
    STG(AOFF(0, 1), Vb, VLDG, cBase + 128, gk2);
    BAR_MID(); PH_MFMA(0, 1, bHi); BAR_END();
    // p7: (1,0) | stage B-lo(t+3)
    PH_READ_A(1, 1);
    STG(BOFF(1, 0), Ab, ALDG, pBase + 0, gk3);
    BAR_MID(); PH_MFMA(1, 0, bLo); BAR_END();
    // p8: (1,1) | stage B-hi(t+3) | vmcnt(4): t+2 ready
    STG(BOFF(1, 1), Ab, ALDG, pBase + 128, gk3);
    BAR_MID(); PH_MFMA(1, 1, bHi);
    asm volatile("s_waitcnt vmcnt(4)" ::: "memory");
    BAR_END();
  }

  // ---- peeled final iter (tiles 62, 63): only A(63) stages remain ----
  {
    const int gk1 = 63 * 128;
    PH_READ_A(0, 0); PH_READ_B(0, 0, bLo);
    STG(AOFF(1, 0), Vb, VLDG, cBase + 0, gk1);
    BAR_MID(); PH_MFMA(0, 0, bLo); BAR_END();
    PH_READ_B(0, 1, bHi);
    STG(AOFF(1, 1), Vb, VLDG, cBase + 128, gk1);
    BAR_MID(); PH_MFMA(0, 1, bHi); BAR_END();
    PH_READ_A(0, 1);
    BAR_MID(); PH_MFMA(1, 0, bLo); BAR_END();
    BAR_MID(); PH_MFMA(1, 1, bHi);
    asm volatile("s_waitcnt vmcnt(0)" ::: "memory");
    BAR_END();
    PH_READ_A(1, 0); PH_READ_B(1, 0, bLo);
    BAR_MID(); PH_MFMA(0, 0, bLo); BAR_END();
    PH_READ_B(1, 1, bHi);
    BAR_MID(); PH_MFMA(0, 1, bHi); BAR_END();
    PH_READ_A(1, 1);
    BAR_MID(); PH_MFMA(1, 0, bLo); BAR_END();
    BAR_MID(); PH_MFMA(1, 1, bHi);
  }

  // ---- epilogue: store acc ----
#pragma unroll
  for (int mi = 0; mi < 8; ++mi)
#pragma unroll
    for (int nj = 0; nj < 4; ++nj) {
      const int col = pBase + wn * 64 + nj * 16 + row16;
      float* orow = Ob + (size_t)(cBase + wm * 128 + mi * 16 + quad * 4) * PP + col;
#pragma unroll
      for (int r = 0; r < 4; ++r)
        orow[(size_t)r * PP] = acc[mi][nj][r];
    }
}

extern "C" void kernel_launch(void* const* d_in, const int* in_sizes, int n_in,
                              void* d_out, int out_size, void* d_ws, size_t ws_size,
                              hipStream_t stream) {
  const float* Xq   = (const float*)d_in[0];
  const float* Xp   = (const float*)d_in[1];
  const float* Wg   = (const float*)d_in[2];
  const float* bias = (const float*)d_in[3];
  float* out = (float*)d_out;

  char* w = (char*)d_ws;
  const size_t MB = 1024 * 1024;
  const size_t CHPP = (size_t)CH * PP;

  if (ws_size >= 481 * MB) {
    // ---- fully batched path: 7 launches ----
    // Wf 1MB @0 | Xt8 128MB @1 | Qh/Ql/Kh/Kl 4x8MB @129..161 | Vbf 64MB @161 | S 256MB @225
    _Float16* Wf       = (_Float16*)w;
    _Float16* Xt8      = (_Float16*)(w + 1 * MB);
    unsigned short* Qh = (unsigned short*)(w + 129 * MB);
    unsigned short* Ql = (unsigned short*)(w + 137 * MB);
    unsigned short* Kh = (unsigned short*)(w + 145 * MB);
    unsigned short* Kl = (unsigned short*)(w + 153 * MB);
    unsigned short* Vbf = (unsigned short*)(w + 161 * MB);
    float* S           = (float*)(w + 225 * MB);

    prep_w<<<512, 256, 0, stream>>>(Wg, Wf);
    tsplit8<<<dim3(PP / 64, CH / 64, 2 * BATCH), 256, 0, stream>>>(Xq, Xp, Xt8);
    proj8<<<dim3(PP / 64, DD / 64, 2 * BATCH), 256, 0, stream>>>(
        Xt8, Wf, bias, Qh, Ql, Kh, Kl);
    scores8<<<dim3(PP / 128, PP / 128, BATCH), 256, 0, stream>>>(Qh, Ql, Kh, Kl, S);
    softmax8<<<dim3(PP, BATCH), 256, 0, stream>>>(S);
    const int n4t = BATCH * CH * PP / 4;
    cvt_bf16<<<n4t / 256, 256, 0, stream>>>(Xp, Vbf, n4t);
    out8<<<dim3(PP / 256, CH / 256, BATCH), 512, 0, stream>>>(
        Vbf, (unsigned short*)S, out);
  } else {
    // ---- legacy 89MB per-batch path (z=0 launches of the same kernels) ----
    _Float16* Xt      = (_Float16*)w;                 // 16 MB (aliased with Vbf)
    unsigned short* Vbf = (unsigned short*)w;         // same region
    _Float16* Wf      = (_Float16*)(w + 16 * MB);     // 1 MB
    unsigned short* Qh = (unsigned short*)(w + 17 * MB);
    unsigned short* Ql = (unsigned short*)(w + 19 * MB);
    unsigned short* Kh = (unsigned short*)(w + 21 * MB);
    unsigned short* Kl = (unsigned short*)(w + 23 * MB);
    float* S          = (float*)(w + 25 * MB);        // 64 MB -> 89 MB total

    prep_w<<<512, 256, 0, stream>>>(Wg, Wf);
    const int n4 = CH * PP / 4;
    for (int b = 0; b < BATCH; ++b) {
      const float* Xqb = Xq + (size_t)b * CHPP;
      const float* Xpb = Xp + (size_t)b * CHPP;
      tsplit8<<<dim3(PP / 64, CH / 64, 1), 256, 0, stream>>>(Xqb, Xqb, Xt);
      proj8<<<dim3(PP / 64, DD / 64, 1), 256, 0, stream>>>(
          Xt, Wf, bias, Qh, Ql, Qh, Ql);
      tsplit8<<<dim3(PP / 64, CH / 64, 1), 256, 0, stream>>>(Xpb, Xpb, Xt);
      proj8<<<dim3(PP / 64, DD / 64, 1), 256, 0, stream>>>(
          Xt, Wf, bias, Kh, Kl, Kh, Kl);
      scores8<<<dim3(PP / 128, PP / 128, 1), 256, 0, stream>>>(Qh, Ql, Kh, Kl, S);
      softmax8<<<dim3(PP, 1), 256, 0, stream>>>(S);
      cvt_bf16<<<n4 / 256, 256, 0, stream>>>(Xpb, Vbf, n4);
      out8<<<dim3(PP / 256, CH / 256, 1), 512, 0, stream>>>(
          Vbf, (unsigned short*)S, out + (size_t)b * CHPP);
    }
  }
}

// Round 2
// 828.482 us; speedup vs baseline: 1.3692x; 1.0560x over previous
//
#include <hip/hip_runtime.h>
#include <math.h>

// AlignmentLayer: B=4, C=2048, H=W=64 (P=4096), HID=256
// R2: scores rewritten on the out8 8-phase template (scr8): 256x256 S-tile,
//     BK=32, LDS rows pack [hi|lo] tensors -> 128B rows, identical swizzle/
//     vmcnt schedule as out8; 3-term bf16 MFMA per k-step. Bit-identical S.
//     cvt_bf16 folded into tsplit8 (writes Vbf for prompt tensors).
// Schedule (iter i, tiles t=2i,t+1; dbuf = tile&1; phases p1..p8):
//   consume: p1-p4 tile t (dbuf0), p5-p8 tile t+1 (dbuf1); quadrants (mh,nh)
//   stage:   p1:Alo(t+1) p2:Ahi(t+1) p3:Blo(t+2) p4:Bhi(t+2)
//            p5:Alo(t+2) p6:Ahi(t+2) p7:Blo(t+3) p8:Bhi(t+3)
//   waits:   vmcnt(4) end-p4 (t+1 ready), vmcnt(4) end-p8 (t+2 ready);
//            every overwrite >=1 phase after last read of that half.

#define BATCH 4
#define CH    2048
#define PP    4096
#define DD    256

typedef __bf16    bf16x8 __attribute__((ext_vector_type(8)));
typedef _Float16  f16x8  __attribute__((ext_vector_type(8)));
typedef _Float16  f16x4  __attribute__((ext_vector_type(4)));
typedef float     f32x4  __attribute__((ext_vector_type(4)));

__device__ __forceinline__ unsigned short f2bf(float f) {
  unsigned int u = __float_as_uint(f);
  unsigned int r = u + 0x7fffu + ((u >> 16) & 1u);   // RNE
  return (unsigned short)(r >> 16);
}

#define GLL(src, dst) \
  __builtin_amdgcn_global_load_lds( \
      (const __attribute__((address_space(1))) unsigned int*)(uintptr_t)(src), \
      (__attribute__((address_space(3))) unsigned int*)(uintptr_t)(dst), 16, 0, 0)

// ---------------- prep_w: W fp32 [o][c] -> fp16 ----------------
__global__ __launch_bounds__(256) void prep_w(
    const float* __restrict__ W, _Float16* __restrict__ Wf) {
  int i = blockIdx.x * 256 + threadIdx.x;          // float4 units, 131072
  float4 v = ((const float4*)W)[i];
  f16x4 h = {(_Float16)v.x, (_Float16)v.y, (_Float16)v.z, (_Float16)v.w};
  ((f16x4*)Wf)[i] = h;
}

// ---------------- tsplit8: X [c][p] fp32 -> Xt [p][c] fp16, batched ----------------
// grid (PP/64, CH/64, NZ), block 256. z: tensor index, b=z>>1, (z&1)? prompt:query.
// doV: for prompt tensors also emit Vbf[c][p] = bf16(X) (replaces cvt pass).
__global__ __launch_bounds__(256) void tsplit8(
    const float* __restrict__ Xq, const float* __restrict__ Xp,
    _Float16* __restrict__ Xt8, unsigned short* __restrict__ Vb8, int doV) {
  const int z = blockIdx.z;
  const float* __restrict__ X =
      ((z & 1) ? Xp : Xq) + (size_t)(z >> 1) * CH * PP;
  _Float16* __restrict__ Xt = Xt8 + (size_t)z * CH * PP;
  unsigned short* __restrict__ Vb = Vb8 + (size_t)(z >> 1) * CH * PP;
  const int emitV = doV & z;   // z&1 && doV

  __shared__ float Ls[64 * 65];
  const int tid = threadIdx.x;
  const int pBase = blockIdx.x * 64, cBase = blockIdx.y * 64;
#pragma unroll
  for (int i = 0; i < 4; ++i) {
    int e = tid + i * 256;               // 0..1023 float4 units
    int c = e >> 4, p4 = e & 15;
    float4 v = *(const float4*)&X[(size_t)(cBase + c) * PP + pBase + p4 * 4];
    Ls[c * 65 + p4 * 4 + 0] = v.x; Ls[c * 65 + p4 * 4 + 1] = v.y;
    Ls[c * 65 + p4 * 4 + 2] = v.z; Ls[c * 65 + p4 * 4 + 3] = v.w;
    if (emitV) {
      ushort4 o;
      o.x = f2bf(v.x); o.y = f2bf(v.y); o.z = f2bf(v.z); o.w = f2bf(v.w);
      *(ushort4*)&Vb[(size_t)(cBase + c) * PP + pBase + p4 * 4] = o;
    }
  }
  __syncthreads();
#pragma unroll
  for (int j = 0; j < 4; ++j) {
    int p = (tid >> 4) + j * 16;         // 0..63
    int c4 = (tid & 15) * 4;
    f16x4 h = {(_Float16)Ls[(c4 + 0) * 65 + p], (_Float16)Ls[(c4 + 1) * 65 + p],
               (_Float16)Ls[(c4 + 2) * 65 + p], (_Float16)Ls[(c4 + 3) * 65 + p]};
    *(f16x4*)&Xt[(size_t)(pBase + p) * CH + cBase + c4] = h;
  }
}

// ---------------- proj8: Y = Xt Wf^T + b -> bf16 hi/lo, batched ----------------
// grid (PP/64, DD/64, NZ). z&1 ? (Kh,Kl) : (Qh,Ql); batch b=z>>1.
__global__ __launch_bounds__(256) void proj8(
    const _Float16* __restrict__ Xt8, const _Float16* __restrict__ Wf,
    const float* __restrict__ bias,
    unsigned short* __restrict__ Qh, unsigned short* __restrict__ Ql,
    unsigned short* __restrict__ Kh, unsigned short* __restrict__ Kl) {
  const int z = blockIdx.z;
  const _Float16* __restrict__ Xt = Xt8 + (size_t)z * CH * PP;
  unsigned short* __restrict__ Yh =
      ((z & 1) ? Kh : Qh) + (size_t)(z >> 1) * PP * DD;
  unsigned short* __restrict__ Yl =
      ((z & 1) ? Kl : Ql) + (size_t)(z >> 1) * PP * DD;

  const int pBase = blockIdx.x * 64;
  const int oBase = blockIdx.y * 64;
  const int tid  = threadIdx.x;
  const int wave = tid >> 6;
  const int lane = tid & 63;
  const int wm = wave & 1, wn = wave >> 1;
  const int row16 = lane & 15, quad = lane >> 4, koff = quad * 8;

  __shared__ __align__(16) _Float16 As0[64 * 32], As1[64 * 32];
  __shared__ __align__(16) _Float16 Bs0[64 * 32], Bs1[64 * 32];

  const int sRow = lane >> 2;            // 0..15
  const int sKc  = (lane & 3) * 8;       // fp16 elems, 16B chunks

  f32x4 acc[2][2];
#pragma unroll
  for (int i = 0; i < 2; ++i)
#pragma unroll
    for (int j = 0; j < 2; ++j) acc[i][j] = (f32x4){0.f, 0.f, 0.f, 0.f};

  for (int c0 = 0; c0 < CH; c0 += 64) {
    const int row = wave * 16 + sRow;    // wave-uniform base + lane scatter
    GLL(&Xt[(size_t)(pBase + row) * CH + c0 + sKc],      &As0[(wave * 16) * 32]);
    GLL(&Xt[(size_t)(pBase + row) * CH + c0 + 32 + sKc], &As1[(wave * 16) * 32]);
    GLL(&Wf[(size_t)(oBase + row) * CH + c0 + sKc],      &Bs0[(wave * 16) * 32]);
    GLL(&Wf[(size_t)(oBase + row) * CH + c0 + 32 + sKc], &Bs1[(wave * 16) * 32]);
    __syncthreads();
#pragma unroll
    for (int s = 0; s < 2; ++s) {
      const _Float16* Ap = s ? As1 : As0;
      const _Float16* Bp = s ? Bs1 : Bs0;
      f16x8 af[2], bf[2];
#pragma unroll
      for (int i = 0; i < 2; ++i)
        af[i] = *(const f16x8*)&Ap[(wm * 32 + i * 16 + row16) * 32 + koff];
#pragma unroll
      for (int j = 0; j < 2; ++j)
        bf[j] = *(const f16x8*)&Bp[(wn * 32 + j * 16 + row16) * 32 + koff];
#pragma unroll
      for (int i = 0; i < 2; ++i)
#pragma unroll
        for (int j = 0; j < 2; ++j)
          acc[i][j] = __builtin_amdgcn_mfma_f32_16x16x32_f16(
              af[i], bf[j], acc[i][j], 0, 0, 0);
    }
    __syncthreads();
  }

#pragma unroll
  for (int i = 0; i < 2; ++i)
#pragma unroll
    for (int j = 0; j < 2; ++j) {
      const int ocol = oBase + wn * 32 + j * 16 + row16;
      const float bv = bias[ocol];
#pragma unroll
      for (int r = 0; r < 4; ++r) {
        const int prow = pBase + wm * 32 + i * 16 + quad * 4 + r;
        float y = acc[i][j][r] + bv;
        unsigned short h = f2bf(y);
        float hf = __uint_as_float((unsigned int)h << 16);
        unsigned short l = f2bf(y - hf);
        Yh[(size_t)prow * DD + ocol] = h;
        Yl[(size_t)prow * DD + ocol] = l;
      }
    }
}

// ---------------- softmax rows; writes bf16 in place, batched ----------------
// grid (PP, NB)
__global__ __launch_bounds__(256) void softmax8(float* __restrict__ S_) {
  float* __restrict__ Sb = S_ + (size_t)blockIdx.y * PP * PP;
  unsigned short* __restrict__ Ab = (unsigned short*)Sb;
  const size_t p = blockIdx.x;
  float* row = Sb + p * PP;
  const int tid = threadIdx.x;
  float4 v[4];
#pragma unroll
  for (int i = 0; i < 4; ++i)
    v[i] = *(const float4*)&row[(i * 256 + tid) * 4];
  float m = -1e30f;
#pragma unroll
  for (int i = 0; i < 4; ++i)
    m = fmaxf(m, fmaxf(fmaxf(v[i].x, v[i].y), fmaxf(v[i].z, v[i].w)));
#pragma unroll
  for (int off = 32; off > 0; off >>= 1)
    m = fmaxf(m, __shfl_xor(m, off));
  __shared__ float red[4];
  const int lane = tid & 63, wv = tid >> 6;
  if (lane == 0) red[wv] = m;
  __syncthreads();
  m = fmaxf(fmaxf(red[0], red[1]), fmaxf(red[2], red[3]));
  __syncthreads();
  float s = 0.f;
#pragma unroll
  for (int i = 0; i < 4; ++i) {
    v[i].x = __expf(v[i].x - m);
    v[i].y = __expf(v[i].y - m);
    v[i].z = __expf(v[i].z - m);
    v[i].w = __expf(v[i].w - m);
    s += v[i].x + v[i].y + v[i].z + v[i].w;
  }
#pragma unroll
  for (int off = 32; off > 0; off >>= 1)
    s += __shfl_xor(s, off);
  if (lane == 0) red[wv] = s;
  __syncthreads();
  s = red[0] + red[1] + red[2] + red[3];
  const float inv = 1.f / s;
  unsigned short* orow = Ab + p * 8192;
#pragma unroll
  for (int i = 0; i < 4; ++i) {
    ushort4 o;
    o.x = f2bf(v[i].x * inv); o.y = f2bf(v[i].y * inv);
    o.z = f2bf(v[i].z * inv); o.w = f2bf(v[i].w * inv);
    *(ushort4*)&orow[(i * 256 + tid) * 4] = o;
  }
}

// ---------------- cvt: fp32 -> bf16 (legacy path only) ----------------
__global__ __launch_bounds__(256) void cvt_bf16(
    const float* __restrict__ X, unsigned short* __restrict__ Y, int n4) {
  int i = blockIdx.x * blockDim.x + threadIdx.x;
  if (i < n4) {
    float4 v = ((const float4*)X)[i];
    ushort4 o;
    o.x = f2bf(v.x); o.y = f2bf(v.y); o.z = f2bf(v.z); o.w = f2bf(v.w);
    ((ushort4*)Y)[i] = o;
  }
}

// ======================= shared 8-phase template machinery =======================
// LDS 128KB: A regions d*32768+h*16384, B at +65536. Rows are 128B (8 chunks of
// 16B); swizzle chunk ^= (row&7), applied on pre-swizzled global source AND read.

#define AOFF(d, h) ((d) * 32768 + (h) * 16384)
#define BOFF(d, h) (65536 + (d) * 32768 + (h) * 16384)

#define PH_READ_A(d, mh) do {                                                  \
  _Pragma("unroll")                                                            \
  for (int m_ = 0; m_ < 4; ++m_) {                                             \
    const int ro_ = AOFF(d, wm) + ((mh) * 64 + m_ * 16 + row16) * 128;         \
    aR[m_][0] = *(const bf16x8*)(Lds + ro_ + cx0);                             \
    aR[m_][1] = *(const bf16x8*)(Lds + ro_ + cx1);                             \
  } } while (0)

#define PH_READ_B(d, nh, breg) do {                                            \
  _Pragma("unroll")                                                            \
  for (int n_ = 0; n_ < 2; ++n_) {                                             \
    const int ro_ = BOFF(d, wnh) + (wnl * 64 + (nh) * 32 + n_ * 16 + row16) * 128; \
    breg[n_][0] = *(const bf16x8*)(Lds + ro_ + cx0);                           \
    breg[n_][1] = *(const bf16x8*)(Lds + ro_ + cx1);                           \
  } } while (0)

// out8 flavor: cx0/cx1 are two successive k-halves of BK=64
#define PH_MFMA(mh, nh, breg) do {                                             \
  __builtin_amdgcn_s_setprio(1);                                               \
  _Pragma("unroll")                                                            \
  for (int m_ = 0; m_ < 4; ++m_)                                               \
  _Pragma("unroll")                                                            \
  for (int n_ = 0; n_ < 2; ++n_) {                                             \
    f32x4 a_ = acc[(mh) * 4 + m_][(nh) * 2 + n_];                              \
    a_ = __builtin_amdgcn_mfma_f32_16x16x32_bf16(aR[m_][0], breg[n_][0], a_, 0, 0, 0); \
    a_ = __builtin_amdgcn_mfma_f32_16x16x32_bf16(aR[m_][1], breg[n_][1], a_, 0, 0, 0); \
    acc[(mh) * 4 + m_][(nh) * 2 + n_] = a_;                                    \
  }                                                                            \
  __builtin_amdgcn_s_setprio(0); } while (0)

// scr8 flavor: cx0 = hi tensor, cx1 = lo tensor, same k; 3-term (hh, hl, lh)
#define PH_MFMA3(mh, nh, breg) do {                                            \
  __builtin_amdgcn_s_setprio(1);                                               \
  _Pragma("unroll")                                                            \
  for (int m_ = 0; m_ < 4; ++m_)                                               \
  _Pragma("unroll")                                                            \
  for (int n_ = 0; n_ < 2; ++n_) {                                             \
    f32x4 a_ = acc[(mh) * 4 + m_][(nh) * 2 + n_];                              \
    a_ = __builtin_amdgcn_mfma_f32_16x16x32_bf16(aR[m_][0], breg[n_][0], a_, 0, 0, 0); \
    a_ = __builtin_amdgcn_mfma_f32_16x16x32_bf16(aR[m_][0], breg[n_][1], a_, 0, 0, 0); \
    a_ = __builtin_amdgcn_mfma_f32_16x16x32_bf16(aR[m_][1], breg[n_][0], a_, 0, 0, 0); \
    acc[(mh) * 4 + m_][(nh) * 2 + n_] = a_;                                    \
  }                                                                            \
  __builtin_amdgcn_s_setprio(0); } while (0)

#define BAR_MID() do {                                                         \
  __builtin_amdgcn_sched_barrier(0);                                           \
  __builtin_amdgcn_s_barrier();                                                \
  asm volatile("s_waitcnt lgkmcnt(0)" ::: "memory");                           \
  __builtin_amdgcn_sched_barrier(0); } while (0)

#define BAR_END() __builtin_amdgcn_s_barrier()

// ---------------- out8: Out = V A^T -- 256x256 tile, 8-phase pipeline ----------------
// V: [CH][PP] bf16 (M side). A: [PP][8192] bf16 rows aliased over fp32 S (N side).
// Out: [CH][PP] fp32. K = PP = 4096, 64 tiles of BK=64.
__global__ __launch_bounds__(512, 2) void out8(
    const unsigned short* __restrict__ V_,
    const unsigned short* __restrict__ A_,
    float* __restrict__ O_) {
  const size_t z = blockIdx.z;
  const unsigned short* __restrict__ Vb = V_ + z * (size_t)CH * PP;
  const unsigned short* __restrict__ Ab = A_ + z * (size_t)PP * 8192;
  float* __restrict__ Ob = O_ + z * (size_t)CH * PP;

  const int pBase = blockIdx.x * 256;   // N (p columns)
  const int cBase = blockIdx.y * 256;   // M (channels)
  const int tid = threadIdx.x;
  const int wave = tid >> 6, lane = tid & 63;
  const int wm = wave >> 2;             // 0..1 (M)
  const int wn = wave & 3;              // 0..3 (N)
  const int wnh = wn >> 1, wnl = wn & 1;
  const int row16 = lane & 15, quad = lane >> 4;

  __shared__ __align__(16) char Lds[131072];

  const int swz = (row16 & 7) << 4;
  const int cx0 = ((quad) << 4) ^ swz;
  const int cx1 = ((4 + quad) << 4) ^ swz;

  const int stRow0 = (wave * 2 + 0) * 8 + (lane >> 3);
  const int stRow1 = (wave * 2 + 1) * 8 + (lane >> 3);
  const int stCol  = (((lane & 7) ^ (lane >> 3)) << 4);
  char* ldsSt0 = Lds + (wave * 2 + 0) * 1024;
  char* ldsSt1 = Lds + (wave * 2 + 1) * 1024;

  const size_t VLDG = (size_t)PP * 2;      // 8192 B
  const size_t ALDG = (size_t)8192 * 2;    // 16384 B

  auto STG = [&](int ldsOff, const void* gbase, size_t ldgB, int rowBase, int gkB) {
    const char* g0 = (const char*)gbase + (size_t)(rowBase + stRow0) * ldgB + gkB + stCol;
    const char* g1 = (const char*)gbase + (size_t)(rowBase + stRow1) * ldgB + gkB + stCol;
    GLL(g0, ldsSt0 + ldsOff);
    GLL(g1, ldsSt1 + ldsOff);
  };

  f32x4 acc[8][4];
#pragma unroll
  for (int i = 0; i < 8; ++i)
#pragma unroll
    for (int j = 0; j < 4; ++j) acc[i][j] = (f32x4){0.f, 0.f, 0.f, 0.f};

  bf16x8 aR[4][2], bLo[2][2], bHi[2][2];

  // ---- prologue: tile0 (B then A) into dbuf0, tile1 B-halves into dbuf1 ----
  STG(BOFF(0, 0), Ab, ALDG, pBase + 0,   0);
  STG(BOFF(0, 1), Ab, ALDG, pBase + 128, 0);
  STG(AOFF(0, 0), Vb, VLDG, cBase + 0,   0);
  STG(AOFF(0, 1), Vb, VLDG, cBase + 128, 0);
  STG(BOFF(1, 0), Ab, ALDG, pBase + 0,   128);
  STG(BOFF(1, 1), Ab, ALDG, pBase + 128, 128);
  asm volatile("s_waitcnt vmcnt(4)" ::: "memory");
  __builtin_amdgcn_s_barrier();

#pragma unroll 1
  for (int i = 0; i < 31; ++i) {
    const int t = 2 * i;
    const int gk1 = (t + 1) * 128, gk2 = (t + 2) * 128, gk3 = (t + 3) * 128;
    PH_READ_A(0, 0); PH_READ_B(0, 0, bLo);
    STG(AOFF(1, 0), Vb, VLDG, cBase + 0, gk1);
    BAR_MID(); PH_MFMA(0, 0, bLo); BAR_END();
    PH_READ_B(0, 1, bHi);
    STG(AOFF(1, 1), Vb, VLDG, cBase + 128, gk1);
    BAR_MID(); PH_MFMA(0, 1, bHi); BAR_END();
    PH_READ_A(0, 1);
    STG(BOFF(0, 0), Ab, ALDG, pBase + 0, gk2);
    BAR_MID(); PH_MFMA(1, 0, bLo); BAR_END();
    STG(BOFF(0, 1), Ab, ALDG, pBase + 128, gk2);
    BAR_MID(); PH_MFMA(1, 1, bHi);
    asm volatile("s_waitcnt vmcnt(4)" ::: "memory");
    BAR_END();
    PH_READ_A(1, 0); PH_READ_B(1, 0, bLo);
    STG(AOFF(0, 0), Vb, VLDG, cBase + 0, gk2);
    BAR_MID(); PH_MFMA(0, 0, bLo); BAR_END();
    PH_READ_B(1, 1, bHi);
    STG(AOFF(0, 1), Vb, VLDG, cBase + 128, gk2);
    BAR_MID(); PH_MFMA(0, 1, bHi); BAR_END();
    PH_READ_A(1, 1);
    STG(BOFF(1, 0), Ab, ALDG, pBase + 0, gk3);
    BAR_MID(); PH_MFMA(1, 0, bLo); BAR_END();
    STG(BOFF(1, 1), Ab, ALDG, pBase + 128, gk3);
    BAR_MID(); PH_MFMA(1, 1, bHi);
    asm volatile("s_waitcnt vmcnt(4)" ::: "memory");
    BAR_END();
  }

  // ---- peeled final iter (tiles 62, 63) ----
  {
    const int gk1 = 63 * 128;
    PH_READ_A(0, 0); PH_READ_B(0, 0, bLo);
    STG(AOFF(1, 0), Vb, VLDG, cBase + 0, gk1);
    BAR_MID(); PH_MFMA(0, 0, bLo); BAR_END();
    PH_READ_B(0, 1, bHi);
    STG(AOFF(1, 1), Vb, VLDG, cBase + 128, gk1);
    BAR_MID(); PH_MFMA(0, 1, bHi); BAR_END();
    PH_READ_A(0, 1);
    BAR_MID(); PH_MFMA(1, 0, bLo); BAR_END();
    BAR_MID(); PH_MFMA(1, 1, bHi);
    asm volatile("s_waitcnt vmcnt(0)" ::: "memory");
    BAR_END();
    PH_READ_A(1, 0); PH_READ_B(1, 0, bLo);
    BAR_MID(); PH_MFMA(0, 0, bLo); BAR_END();
    PH_READ_B(1, 1, bHi);
    BAR_MID(); PH_MFMA(0, 1, bHi); BAR_END();
    PH_READ_A(1, 1);
    BAR_MID(); PH_MFMA(1, 0, bLo); BAR_END();
    BAR_MID(); PH_MFMA(1, 1, bHi);
  }

#pragma unroll
  for (int mi = 0; mi < 8; ++mi)
#pragma unroll
    for (int nj = 0; nj < 4; ++nj) {
      const int col = pBase + wn * 64 + nj * 16 + row16;
      float* orow = Ob + (size_t)(cBase + wm * 128 + mi * 16 + quad * 4) * PP + col;
#pragma unroll
      for (int r = 0; r < 4; ++r)
        orow[(size_t)r * PP] = acc[mi][nj][r];
    }
}

// ---------------- scr8: S = (Qh+Ql)(Kh+Kl)^T -- 256x256 tile, 8-phase ----------------
// Same template as out8. LDS row = 128B packing [hi (chunks 0-3) | lo (chunks 4-7)]
// of one k-tile (BK=32 cols x 2B = 64B per tensor). K=256 -> 8 k-tiles, 3 iters+peel.
// Per-lane staging source selects Qh/Ql (Kh/Kl) by pre-swizzled chunk index.
__global__ __launch_bounds__(512, 2) void scr8(
    const unsigned short* __restrict__ Qh_, const unsigned short* __restrict__ Ql_,
    const unsigned short* __restrict__ Kh_, const unsigned short* __restrict__ Kl_,
    float* __restrict__ S_) {
  const size_t z = blockIdx.z;
  const unsigned short* __restrict__ Qh = Qh_ + z * (size_t)PP * DD;
  const unsigned short* __restrict__ Ql = Ql_ + z * (size_t)PP * DD;
  const unsigned short* __restrict__ Kh = Kh_ + z * (size_t)PP * DD;
  const unsigned short* __restrict__ Kl = Kl_ + z * (size_t)PP * DD;
  float* __restrict__ S = S_ + z * (size_t)PP * PP;

  const int kBase = blockIdx.x * 256;   // N (key columns)
  const int pBase = blockIdx.y * 256;   // M (query rows)
  const int tid = threadIdx.x;
  const int wave = tid >> 6, lane = tid & 63;
  const int wm = wave >> 2;             // 0..1 (M)
  const int wn = wave & 3;              // 0..3 (N)
  const int wnh = wn >> 1, wnl = wn & 1;
  const int row16 = lane & 15, quad = lane >> 4;

  __shared__ __align__(16) char Lds[131072];

  // read swizzle: cx0 -> hi tensor chunk quad, cx1 -> lo tensor chunk quad
  const int swz = (row16 & 7) << 4;
  const int cx0 = ((quad) << 4) ^ swz;
  const int cx1 = ((4 + quad) << 4) ^ swz;

  // staging: lane covers LDS slot (row = lane>>3, chunk = lane&7) within a
  // 8-row x 128B group; logical chunk cc = (lane&7)^(lane>>3); cc<4 -> hi, else lo
  const int stRow0 = (wave * 2 + 0) * 8 + (lane >> 3);
  const int stRow1 = (wave * 2 + 1) * 8 + (lane >> 3);
  const int cc   = (lane & 7) ^ (lane >> 3);
  const int ccB  = (cc & 3) * 16;            // byte within the tensor's k-slice
  const char* tQ = (const char*)((cc >> 2) ? Ql : Qh);
  const char* tK = (const char*)((cc >> 2) ? Kl : Kh);
  char* ldsSt0 = Lds + (wave * 2 + 0) * 1024;
  char* ldsSt1 = Lds + (wave * 2 + 1) * 1024;

  // row stride of Q/K arrays: DD*2 = 512B; k-tile t at byte t*64
  auto STG = [&](int ldsOff, const char* tbase, int rowBase, int tkB) {
    const char* g0 = tbase + (size_t)(rowBase + stRow0) * 512 + tkB + ccB;
    const char* g1 = tbase + (size_t)(rowBase + stRow1) * 512 + tkB + ccB;
    GLL(g0, ldsSt0 + ldsOff);
    GLL(g1, ldsSt1 + ldsOff);
  };

  f32x4 acc[8][4];
#pragma unroll
  for (int i = 0; i < 8; ++i)
#pragma unroll
    for (int j = 0; j < 4; ++j) acc[i][j] = (f32x4){0.f, 0.f, 0.f, 0.f};

  bf16x8 aR[4][2], bLo[2][2], bHi[2][2];

  // ---- prologue: tile0 B+A into dbuf0, tile1 B-halves into dbuf1 ----
  STG(BOFF(0, 0), tK, kBase + 0,   0);
  STG(BOFF(0, 1), tK, kBase + 128, 0);
  STG(AOFF(0, 0), tQ, pBase + 0,   0);
  STG(AOFF(0, 1), tQ, pBase + 128, 0);
  STG(BOFF(1, 0), tK, kBase + 0,   64);
  STG(BOFF(1, 1), tK, kBase + 128, 64);
  asm volatile("s_waitcnt vmcnt(4)" ::: "memory");
  __builtin_amdgcn_s_barrier();

  // ---- main loop: iters 0..2 (k-tiles 0..5), peel tiles 6,7 ----
#pragma unroll 1
  for (int i = 0; i < 3; ++i) {
    const int t = 2 * i;
    const int gk1 = (t + 1) * 64, gk2 = (t + 2) * 64, gk3 = (t + 3) * 64;
    PH_READ_A(0, 0); PH_READ_B(0, 0, bLo);
    STG(AOFF(1, 0), tQ, pBase + 0, gk1);
    BAR_MID(); PH_MFMA3(0, 0, bLo); BAR_END();
    PH_READ_B(0, 1, bHi);
    STG(AOFF(1, 1), tQ, pBase + 128, gk1);
    BAR_MID(); PH_MFMA3(0, 1, bHi); BAR_END();
    PH_READ_A(0, 1);
    STG(BOFF(0, 0), tK, kBase + 0, gk2);
    BAR_MID(); PH_MFMA3(1, 0, bLo); BAR_END();
    STG(BOFF(0, 1), tK, kBase + 128, gk2);
    BAR_MID(); PH_MFMA3(1, 1, bHi);
    asm volatile("s_waitcnt vmcnt(4)" ::: "memory");
    BAR_END();
    PH_READ_A(1, 0); PH_READ_B(1, 0, bLo);
    STG(AOFF(0, 0), tQ, pBase + 0, gk2);
    BAR_MID(); PH_MFMA3(0, 0, bLo); BAR_END();
    PH_READ_B(1, 1, bHi);
    STG(AOFF(0, 1), tQ, pBase + 128, gk2);
    BAR_MID(); PH_MFMA3(0, 1, bHi); BAR_END();
    PH_READ_A(1, 1);
    STG(BOFF(1, 0), tK, kBase + 0, gk3);
    BAR_MID(); PH_MFMA3(1, 0, bLo); BAR_END();
    STG(BOFF(1, 1), tK, kBase + 128, gk3);
    BAR_MID(); PH_MFMA3(1, 1, bHi);
    asm volatile("s_waitcnt vmcnt(4)" ::: "memory");
    BAR_END();
  }

  // ---- peeled final iter (k-tiles 6, 7): only A(7) stages remain ----
  {
    const int gk1 = 7 * 64;
    PH_READ_A(0, 0); PH_READ_B(0, 0, bLo);
    STG(AOFF(1, 0), tQ, pBase + 0, gk1);
    BAR_MID(); PH_MFMA3(0, 0, bLo); BAR_END();
    PH_READ_B(0, 1, bHi);
    STG(AOFF(1, 1), tQ, pBase + 128, gk1);
    BAR_MID(); PH_MFMA3(0, 1, bHi); BAR_END();
    PH_READ_A(0, 1);
    BAR_MID(); PH_MFMA3(1, 0, bLo); BAR_END();
    BAR_MID(); PH_MFMA3(1, 1, bHi);
    asm volatile("s_waitcnt vmcnt(0)" ::: "memory");
    BAR_END();
    PH_READ_A(1, 0); PH_READ_B(1, 0, bLo);
    BAR_MID(); PH_MFMA3(0, 0, bLo); BAR_END();
    PH_READ_B(1, 1, bHi);
    BAR_MID(); PH_MFMA3(0, 1, bHi); BAR_END();
    PH_READ_A(1, 1);
    BAR_MID(); PH_MFMA3(1, 0, bLo); BAR_END();
    BAR_MID(); PH_MFMA3(1, 1, bHi);
  }

  // ---- epilogue: store S fp32 ----
#pragma unroll
  for (int mi = 0; mi < 8; ++mi)
#pragma unroll
    for (int nj = 0; nj < 4; ++nj) {
      const int kcol = kBase + wn * 64 + nj * 16 + row16;
      float* orow = S + (size_t)(pBase + wm * 128 + mi * 16 + quad * 4) * PP + kcol;
#pragma unroll
      for (int r = 0; r < 4; ++r)
        orow[(size_t)r * PP] = acc[mi][nj][r];
    }
}

extern "C" void kernel_launch(void* const* d_in, const int* in_sizes, int n_in,
                              void* d_out, int out_size, void* d_ws, size_t ws_size,
                              hipStream_t stream) {
  const float* Xq   = (const float*)d_in[0];
  const float* Xp   = (const float*)d_in[1];
  const float* Wg   = (const float*)d_in[2];
  const float* bias = (const float*)d_in[3];
  float* out = (float*)d_out;

  char* w = (char*)d_ws;
  const size_t MB = 1024 * 1024;
  const size_t CHPP = (size_t)CH * PP;

  if (ws_size >= 481 * MB) {
    // ---- fully batched path: 6 launches ----
    _Float16* Wf       = (_Float16*)w;
    _Float16* Xt8      = (_Float16*)(w + 1 * MB);
    unsigned short* Qh = (unsigned short*)(w + 129 * MB);
    unsigned short* Ql = (unsigned short*)(w + 137 * MB);
    unsigned short* Kh = (unsigned short*)(w + 145 * MB);
    unsigned short* Kl = (unsigned short*)(w + 153 * MB);
    unsigned short* Vbf = (unsigned short*)(w + 161 * MB);
    float* S           = (float*)(w + 225 * MB);

    prep_w<<<512, 256, 0, stream>>>(Wg, Wf);
    tsplit8<<<dim3(PP / 64, CH / 64, 2 * BATCH), 256, 0, stream>>>(
        Xq, Xp, Xt8, Vbf, 1);
    proj8<<<dim3(PP / 64, DD / 64, 2 * BATCH), 256, 0, stream>>>(
        Xt8, Wf, bias, Qh, Ql, Kh, Kl);
    scr8<<<dim3(PP / 256, PP / 256, BATCH), 512, 0, stream>>>(Qh, Ql, Kh, Kl, S);
    softmax8<<<dim3(PP, BATCH), 256, 0, stream>>>(S);
    out8<<<dim3(PP / 256, CH / 256, BATCH), 512, 0, stream>>>(
        Vbf, (unsigned short*)S, out);
  } else {
    // ---- legacy 89MB per-batch path ----
    _Float16* Xt      = (_Float16*)w;                 // 16 MB (aliased with Vbf)
    unsigned short* Vbf = (unsigned short*)w;         // same region
    _Float16* Wf      = (_Float16*)(w + 16 * MB);     // 1 MB
    unsigned short* Qh = (unsigned short*)(w + 17 * MB);
    unsigned short* Ql = (unsigned short*)(w + 19 * MB);
    unsigned short* Kh = (unsigned short*)(w + 21 * MB);
    unsigned short* Kl = (unsigned short*)(w + 23 * MB);
    float* S          = (float*)(w + 25 * MB);        // 64 MB -> 89 MB total

    prep_w<<<512, 256, 0, stream>>>(Wg, Wf);
    const int n4 = CH * PP / 4;
    for (int b = 0; b < BATCH; ++b) {
      const float* Xqb = Xq + (size_t)b * CHPP;
      const float* Xpb = Xp + (size_t)b * CHPP;
      tsplit8<<<dim3(PP / 64, CH / 64, 1), 256, 0, stream>>>(
          Xqb, Xqb, Xt, Vbf, 0);
      proj8<<<dim3(PP / 64, DD / 64, 1), 256, 0, stream>>>(
          Xt, Wf, bias, Qh, Ql, Qh, Ql);
      tsplit8<<<dim3(PP / 64, CH / 64, 1), 256, 0, stream>>>(
          Xpb, Xpb, Xt, Vbf, 0);
      proj8<<<dim3(PP / 64, DD / 64, 1), 256, 0, stream>>>(
          Xt, Wf, bias, Kh, Kl, Kh, Kl);
      scr8<<<dim3(PP / 256, PP / 256, 1), 512, 0, stream>>>(Qh, Ql, Kh, Kl, S);
      softmax8<<<dim3(PP, 1), 256, 0, stream>>>(S);
      cvt_bf16<<<n4 / 256, 256, 0, stream>>>(Xpb, Vbf, n4);
      out8<<<dim3(PP / 256, CH / 256, 1), 512, 0, stream>>>(
          Vbf, (unsigned short*)S, out + (size_t)b * CHPP);
    }
  }
}

// Round 3
// 730.811 us; speedup vs baseline: 1.5521x; 1.1336x over previous
//
#include <hip/hip_runtime.h>
#include <math.h>

// AlignmentLayer: B=4, C=2048, H=W=64 (P=4096), HID=256
// R3: tsplit8+proj8 replaced by fused projX (no Xt intermediate):
//     - X[64c][64p] fp32 staged linearly via global_load_lds, transposed at
//       fragment-build time (b32 column reads + cvt f16, 4-way conflict ok)
//     - W[256o][64c] fp16 staged in 128B swizzled rows (out8 T2 pattern)
//     - Vbf emitted from the staged LDS tile for prompt slices
//     MFMA operand/order identical to old proj8 -> bit-identical outputs.
// Pipeline: prep_w, projX, scr8 (8-phase), softmax8, out8 (8-phase). 5 launches.

#define BATCH 4
#define CH    2048
#define PP    4096
#define DD    256

typedef __bf16    bf16x8 __attribute__((ext_vector_type(8)));
typedef _Float16  f16x8  __attribute__((ext_vector_type(8)));
typedef _Float16  f16x4  __attribute__((ext_vector_type(4)));
typedef float     f32x4  __attribute__((ext_vector_type(4)));

__device__ __forceinline__ unsigned short f2bf(float f) {
  unsigned int u = __float_as_uint(f);
  unsigned int r = u + 0x7fffu + ((u >> 16) & 1u);   // RNE
  return (unsigned short)(r >> 16);
}

#define GLL(src, dst) \
  __builtin_amdgcn_global_load_lds( \
      (const __attribute__((address_space(1))) unsigned int*)(uintptr_t)(src), \
      (__attribute__((address_space(3))) unsigned int*)(uintptr_t)(dst), 16, 0, 0)

// ---------------- prep_w: W fp32 [o][c] -> fp16 ----------------
__global__ __launch_bounds__(256) void prep_w(
    const float* __restrict__ W, _Float16* __restrict__ Wf) {
  int i = blockIdx.x * 256 + threadIdx.x;          // float4 units, 131072
  float4 v = ((const float4*)W)[i];
  f16x4 h = {(_Float16)v.x, (_Float16)v.y, (_Float16)v.z, (_Float16)v.w};
  ((f16x4*)Wf)[i] = h;
}

// ---------------- projX: Q/K projection fused with transpose ----------------
// grid (PP/64, 1, NZ), block 256 (4 waves). z' = zbase + blockIdx.z:
//   tensor = (z'&1) ? prompt : query, batch = z'>>1.
// Block computes Y[pBase..+63][0..255] = sum_c X[c][p] * Wf[o][c] + bias[o],
// writing bf16 hi/lo. For prompt slices also emits Vbf[c][p] = bf16(X[c][p]).
// LDS: Ws 32KB (256 rows x 128B, XOR-swizzled chunks) + LsX 16KB (64c x 64p f32,
// linear). K-loop c0 += 64; per s-half (32c): af built by LDS transpose reads,
// bf read as f16x8 from swizzled rows. MFMA order == old proj8 (bit-identical).
__global__ __launch_bounds__(256) void projX(
    const float* __restrict__ Xq, const float* __restrict__ Xp,
    const _Float16* __restrict__ Wf, const float* __restrict__ bias,
    unsigned short* __restrict__ Qh, unsigned short* __restrict__ Ql,
    unsigned short* __restrict__ Kh, unsigned short* __restrict__ Kl,
    unsigned short* __restrict__ Vb8, int zbase, int single) {
  const int z = zbase + blockIdx.z;
  const int b = z >> 1;
  const int ob = single ? 0 : b;
  const float* __restrict__ X =
      ((z & 1) ? Xp : Xq) + (size_t)b * CH * PP;
  unsigned short* __restrict__ Yh =
      ((z & 1) ? Kh : Qh) + (size_t)ob * PP * DD;
  unsigned short* __restrict__ Yl =
      ((z & 1) ? Kl : Ql) + (size_t)ob * PP * DD;
  unsigned short* __restrict__ Vb = Vb8 + (size_t)ob * CH * PP;
  const int emitV = (z & 1);

  const int pBase = blockIdx.x * 64;
  const int tid  = threadIdx.x;
  const int wave = tid >> 6;
  const int lane = tid & 63;
  const int row16 = lane & 15, quad = lane >> 4;

  __shared__ __align__(16) char LdsP[32768 + 16384];
  char*  Ws  = LdsP;                       // [256 o][128 B] swizzled
  float* LsX = (float*)(LdsP + 32768);     // [64 c][64 p] linear

  // W staging (out8 STG pattern): 8 instr/wave, 8 rows each
  const int wRowIn  = lane >> 3;                         // 0..7
  const int wChunk  = (((lane & 7) ^ (lane >> 3)) << 4); // pre-swizzled src chunk
  // X staging: 4 instr/wave, 4 rows each (16 lanes x 16B per row)
  const int xRowIn  = lane >> 4;                         // 0..3
  const int xColB   = (lane & 15) * 16;                  // bytes within 256B row

  f32x4 acc[4][4];
#pragma unroll
  for (int i = 0; i < 4; ++i)
#pragma unroll
    for (int j = 0; j < 4; ++j) acc[i][j] = (f32x4){0.f, 0.f, 0.f, 0.f};

#pragma unroll 1
  for (int c0 = 0; c0 < CH; c0 += 64) {
    // ---- stage W[all 256 o][c0..c0+63] into swizzled 128B rows ----
#pragma unroll
    for (int q = 0; q < 8; ++q) {
      const int g = wave * 8 + q;                        // 0..31
      const char* src = (const char*)Wf +
          (size_t)(g * 8 + wRowIn) * (CH * 2) + c0 * 2 + wChunk;
      GLL(src, Ws + g * 1024);
    }
    // ---- stage X[c0..c0+63][pBase..pBase+63] fp32 linear ----
#pragma unroll
    for (int q = 0; q < 4; ++q) {
      const int g = wave * 4 + q;                        // 0..15
      const char* src = (const char*)X +
          ((size_t)(c0 + g * 4 + xRowIn) * PP + pBase) * 4 + xColB;
      GLL(src, (char*)LsX + g * 1024);
    }
    __syncthreads();

    // ---- compute: two 32-wide k-halves, order matches old proj8 ----
#pragma unroll
    for (int s = 0; s < 2; ++s) {
      f16x8 af[4], bf[4];
#pragma unroll
      for (int i = 0; i < 4; ++i) {
        f16x8 a;
#pragma unroll
        for (int e = 0; e < 8; ++e)
          a[e] = (_Float16)LsX[(s * 32 + quad * 8 + e) * 64 + i * 16 + row16];
        af[i] = a;
      }
#pragma unroll
      for (int j = 0; j < 4; ++j) {
        const int brow = wave * 64 + j * 16 + row16;
        bf[j] = *(const f16x8*)(Ws + brow * 128 +
                                (((s * 4 + quad) ^ (row16 & 7)) << 4));
      }
#pragma unroll
      for (int i = 0; i < 4; ++i)
#pragma unroll
        for (int j = 0; j < 4; ++j)
          acc[i][j] = __builtin_amdgcn_mfma_f32_16x16x32_f16(
              af[i], bf[j], acc[i][j], 0, 0, 0);
    }

    // ---- emit V from the staged tile (prompt slices) ----
    if (emitV) {
      const int cl = tid >> 2, ps = (tid & 3) * 16;
      const float* xr = &LsX[cl * 64 + ps];
      unsigned short tmp[16];
#pragma unroll
      for (int u = 0; u < 16; ++u) tmp[u] = f2bf(xr[u]);
      char* dst = (char*)Vb + ((size_t)(c0 + cl) * PP + pBase + ps) * 2;
      *(uint4*)dst        = *(const uint4*)tmp;
      *(uint4*)(dst + 16) = *(const uint4*)(tmp + 8);
    }
    __syncthreads();
  }

  // ---- epilogue: bias + bf16 hi/lo split (identical to old proj8) ----
#pragma unroll
  for (int i = 0; i < 4; ++i)
#pragma unroll
    for (int j = 0; j < 4; ++j) {
      const int ocol = wave * 64 + j * 16 + row16;
      const float bv = bias[ocol];
#pragma unroll
      for (int r = 0; r < 4; ++r) {
        const int prow = pBase + i * 16 + quad * 4 + r;
        float y = acc[i][j][r] + bv;
        unsigned short h = f2bf(y);
        float hf = __uint_as_float((unsigned int)h << 16);
        unsigned short l = f2bf(y - hf);
        Yh[(size_t)prow * DD + ocol] = h;
        Yl[(size_t)prow * DD + ocol] = l;
      }
    }
}

// ---------------- softmax rows; writes bf16 in place, batched ----------------
// grid (PP, NB)
__global__ __launch_bounds__(256) void softmax8(float* __restrict__ S_) {
  float* __restrict__ Sb = S_ + (size_t)blockIdx.y * PP * PP;
  unsigned short* __restrict__ Ab = (unsigned short*)Sb;
  const size_t p = blockIdx.x;
  float* row = Sb + p * PP;
  const int tid = threadIdx.x;
  float4 v[4];
#pragma unroll
  for (int i = 0; i < 4; ++i)
    v[i] = *(const float4*)&row[(i * 256 + tid) * 4];
  float m = -1e30f;
#pragma unroll
  for (int i = 0; i < 4; ++i)
    m = fmaxf(m, fmaxf(fmaxf(v[i].x, v[i].y), fmaxf(v[i].z, v[i].w)));
#pragma unroll
  for (int off = 32; off > 0; off >>= 1)
    m = fmaxf(m, __shfl_xor(m, off));
  __shared__ float red[4];
  const int lane = tid & 63, wv = tid >> 6;
  if (lane == 0) red[wv] = m;
  __syncthreads();
  m = fmaxf(fmaxf(red[0], red[1]), fmaxf(red[2], red[3]));
  __syncthreads();
  float s = 0.f;
#pragma unroll
  for (int i = 0; i < 4; ++i) {
    v[i].x = __expf(v[i].x - m);
    v[i].y = __expf(v[i].y - m);
    v[i].z = __expf(v[i].z - m);
    v[i].w = __expf(v[i].w - m);
    s += v[i].x + v[i].y + v[i].z + v[i].w;
  }
#pragma unroll
  for (int off = 32; off > 0; off >>= 1)
    s += __shfl_xor(s, off);
  if (lane == 0) red[wv] = s;
  __syncthreads();
  s = red[0] + red[1] + red[2] + red[3];
  const float inv = 1.f / s;
  unsigned short* orow = Ab + p * 8192;
#pragma unroll
  for (int i = 0; i < 4; ++i) {
    ushort4 o;
    o.x = f2bf(v[i].x * inv); o.y = f2bf(v[i].y * inv);
    o.z = f2bf(v[i].z * inv); o.w = f2bf(v[i].w * inv);
    *(ushort4*)&orow[(i * 256 + tid) * 4] = o;
  }
}

// ======================= shared 8-phase template machinery =======================
// LDS 128KB: A regions d*32768+h*16384, B at +65536. Rows are 128B (8 chunks of
// 16B); swizzle chunk ^= (row&7), applied on pre-swizzled global source AND read.

#define AOFF(d, h) ((d) * 32768 + (h) * 16384)
#define BOFF(d, h) (65536 + (d) * 32768 + (h) * 16384)

#define PH_READ_A(d, mh) do {                                                  \
  _Pragma("unroll")                                                            \
  for (int m_ = 0; m_ < 4; ++m_) {                                             \
    const int ro_ = AOFF(d, wm) + ((mh) * 64 + m_ * 16 + row16) * 128;         \
    aR[m_][0] = *(const bf16x8*)(Lds + ro_ + cx0);                             \
    aR[m_][1] = *(const bf16x8*)(Lds + ro_ + cx1);                             \
  } } while (0)

#define PH_READ_B(d, nh, breg) do {                                            \
  _Pragma("unroll")                                                            \
  for (int n_ = 0; n_ < 2; ++n_) {                                             \
    const int ro_ = BOFF(d, wnh) + (wnl * 64 + (nh) * 32 + n_ * 16 + row16) * 128; \
    breg[n_][0] = *(const bf16x8*)(Lds + ro_ + cx0);                           \
    breg[n_][1] = *(const bf16x8*)(Lds + ro_ + cx1);                           \
  } } while (0)

// out8 flavor: cx0/cx1 are two successive k-halves of BK=64
#define PH_MFMA(mh, nh, breg) do {                                             \
  __builtin_amdgcn_s_setprio(1);                                               \
  _Pragma("unroll")                                                            \
  for (int m_ = 0; m_ < 4; ++m_)                                               \
  _Pragma("unroll")                                                            \
  for (int n_ = 0; n_ < 2; ++n_) {                                             \
    f32x4 a_ = acc[(mh) * 4 + m_][(nh) * 2 + n_];                              \
    a_ = __builtin_amdgcn_mfma_f32_16x16x32_bf16(aR[m_][0], breg[n_][0], a_, 0, 0, 0); \
    a_ = __builtin_amdgcn_mfma_f32_16x16x32_bf16(aR[m_][1], breg[n_][1], a_, 0, 0, 0); \
    acc[(mh) * 4 + m_][(nh) * 2 + n_] = a_;                                    \
  }                                                                            \
  __builtin_amdgcn_s_setprio(0); } while (0)

// scr8 flavor: cx0 = hi tensor, cx1 = lo tensor, same k; 3-term (hh, hl, lh)
#define PH_MFMA3(mh, nh, breg) do {                                            \
  __builtin_amdgcn_s_setprio(1);                                               \
  _Pragma("unroll")                                                            \
  for (int m_ = 0; m_ < 4; ++m_)                                               \
  _Pragma("unroll")                                                            \
  for (int n_ = 0; n_ < 2; ++n_) {                                             \
    f32x4 a_ = acc[(mh) * 4 + m_][(nh) * 2 + n_];                              \
    a_ = __builtin_amdgcn_mfma_f32_16x16x32_bf16(aR[m_][0], breg[n_][0], a_, 0, 0, 0); \
    a_ = __builtin_amdgcn_mfma_f32_16x16x32_bf16(aR[m_][0], breg[n_][1], a_, 0, 0, 0); \
    a_ = __builtin_amdgcn_mfma_f32_16x16x32_bf16(aR[m_][1], breg[n_][0], a_, 0, 0, 0); \
    acc[(mh) * 4 + m_][(nh) * 2 + n_] = a_;                                    \
  }                                                                            \
  __builtin_amdgcn_s_setprio(0); } while (0)

#define BAR_MID() do {                                                         \
  __builtin_amdgcn_sched_barrier(0);                                           \
  __builtin_amdgcn_s_barrier();                                                \
  asm volatile("s_waitcnt lgkmcnt(0)" ::: "memory");                           \
  __builtin_amdgcn_sched_barrier(0); } while (0)

#define BAR_END() __builtin_amdgcn_s_barrier()

// ---------------- out8: Out = V A^T -- 256x256 tile, 8-phase pipeline ----------------
// V: [CH][PP] bf16 (M side). A: [PP][8192] bf16 rows aliased over fp32 S (N side).
// Out: [CH][PP] fp32. K = PP = 4096, 64 tiles of BK=64.
__global__ __launch_bounds__(512, 2) void out8(
    const unsigned short* __restrict__ V_,
    const unsigned short* __restrict__ A_,
    float* __restrict__ O_) {
  const size_t z = blockIdx.z;
  const unsigned short* __restrict__ Vb = V_ + z * (size_t)CH * PP;
  const unsigned short* __restrict__ Ab = A_ + z * (size_t)PP * 8192;
  float* __restrict__ Ob = O_ + z * (size_t)CH * PP;

  const int pBase = blockIdx.x * 256;   // N (p columns)
  const int cBase = blockIdx.y * 256;   // M (channels)
  const int tid = threadIdx.x;
  const int wave = tid >> 6, lane = tid & 63;
  const int wm = wave >> 2;             // 0..1 (M)
  const int wn = wave & 3;              // 0..3 (N)
  const int wnh = wn >> 1, wnl = wn & 1;
  const int row16 = lane & 15, quad = lane >> 4;

  __shared__ __align__(16) char Lds[131072];

  const int swz = (row16 & 7) << 4;
  const int cx0 = ((quad) << 4) ^ swz;
  const int cx1 = ((4 + quad) << 4) ^ swz;

  const int stRow0 = (wave * 2 + 0) * 8 + (lane >> 3);
  const int stRow1 = (wave * 2 + 1) * 8 + (lane >> 3);
  const int stCol  = (((lane & 7) ^ (lane >> 3)) << 4);
  char* ldsSt0 = Lds + (wave * 2 + 0) * 1024;
  char* ldsSt1 = Lds + (wave * 2 + 1) * 1024;

  const size_t VLDG = (size_t)PP * 2;      // 8192 B
  const size_t ALDG = (size_t)8192 * 2;    // 16384 B

  auto STG = [&](int ldsOff, const void* gbase, size_t ldgB, int rowBase, int gkB) {
    const char* g0 = (const char*)gbase + (size_t)(rowBase + stRow0) * ldgB + gkB + stCol;
    const char* g1 = (const char*)gbase + (size_t)(rowBase + stRow1) * ldgB + gkB + stCol;
    GLL(g0, ldsSt0 + ldsOff);
    GLL(g1, ldsSt1 + ldsOff);
  };

  f32x4 acc[8][4];
#pragma unroll
  for (int i = 0; i < 8; ++i)
#pragma unroll
    for (int j = 0; j < 4; ++j) acc[i][j] = (f32x4){0.f, 0.f, 0.f, 0.f};

  bf16x8 aR[4][2], bLo[2][2], bHi[2][2];

  // ---- prologue: tile0 (B then A) into dbuf0, tile1 B-halves into dbuf1 ----
  STG(BOFF(0, 0), Ab, ALDG, pBase + 0,   0);
  STG(BOFF(0, 1), Ab, ALDG, pBase + 128, 0);
  STG(AOFF(0, 0), Vb, VLDG, cBase + 0,   0);
  STG(AOFF(0, 1), Vb, VLDG, cBase + 128, 0);
  STG(BOFF(1, 0), Ab, ALDG, pBase + 0,   128);
  STG(BOFF(1, 1), Ab, ALDG, pBase + 128, 128);
  asm volatile("s_waitcnt vmcnt(4)" ::: "memory");
  __builtin_amdgcn_s_barrier();

#pragma unroll 1
  for (int i = 0; i < 31; ++i) {
    const int t = 2 * i;
    const int gk1 = (t + 1) * 128, gk2 = (t + 2) * 128, gk3 = (t + 3) * 128;
    PH_READ_A(0, 0); PH_READ_B(0, 0, bLo);
    STG(AOFF(1, 0), Vb, VLDG, cBase + 0, gk1);
    BAR_MID(); PH_MFMA(0, 0, bLo); BAR_END();
    PH_READ_B(0, 1, bHi);
    STG(AOFF(1, 1), Vb, VLDG, cBase + 128, gk1);
    BAR_MID(); PH_MFMA(0, 1, bHi); BAR_END();
    PH_READ_A(0, 1);
    STG(BOFF(0, 0), Ab, ALDG, pBase + 0, gk2);
    BAR_MID(); PH_MFMA(1, 0, bLo); BAR_END();
    STG(BOFF(0, 1), Ab, ALDG, pBase + 128, gk2);
    BAR_MID(); PH_MFMA(1, 1, bHi);
    asm volatile("s_waitcnt vmcnt(4)" ::: "memory");
    BAR_END();
    PH_READ_A(1, 0); PH_READ_B(1, 0, bLo);
    STG(AOFF(0, 0), Vb, VLDG, cBase + 0, gk2);
    BAR_MID(); PH_MFMA(0, 0, bLo); BAR_END();
    PH_READ_B(1, 1, bHi);
    STG(AOFF(0, 1), Vb, VLDG, cBase + 128, gk2);
    BAR_MID(); PH_MFMA(0, 1, bHi); BAR_END();
    PH_READ_A(1, 1);
    STG(BOFF(1, 0), Ab, ALDG, pBase + 0, gk3);
    BAR_MID(); PH_MFMA(1, 0, bLo); BAR_END();
    STG(BOFF(1, 1), Ab, ALDG, pBase + 128, gk3);
    BAR_MID(); PH_MFMA(1, 1, bHi);
    asm volatile("s_waitcnt vmcnt(4)" ::: "memory");
    BAR_END();
  }

  // ---- peeled final iter (tiles 62, 63) ----
  {
    const int gk1 = 63 * 128;
    PH_READ_A(0, 0); PH_READ_B(0, 0, bLo);
    STG(AOFF(1, 0), Vb, VLDG, cBase + 0, gk1);
    BAR_MID(); PH_MFMA(0, 0, bLo); BAR_END();
    PH_READ_B(0, 1, bHi);
    STG(AOFF(1, 1), Vb, VLDG, cBase + 128, gk1);
    BAR_MID(); PH_MFMA(0, 1, bHi); BAR_END();
    PH_READ_A(0, 1);
    BAR_MID(); PH_MFMA(1, 0, bLo); BAR_END();
    BAR_MID(); PH_MFMA(1, 1, bHi);
    asm volatile("s_waitcnt vmcnt(0)" ::: "memory");
    BAR_END();
    PH_READ_A(1, 0); PH_READ_B(1, 0, bLo);
    BAR_MID(); PH_MFMA(0, 0, bLo); BAR_END();
    PH_READ_B(1, 1, bHi);
    BAR_MID(); PH_MFMA(0, 1, bHi); BAR_END();
    PH_READ_A(1, 1);
    BAR_MID(); PH_MFMA(1, 0, bLo); BAR_END();
    BAR_MID(); PH_MFMA(1, 1, bHi);
  }

#pragma unroll
  for (int mi = 0; mi < 8; ++mi)
#pragma unroll
    for (int nj = 0; nj < 4; ++nj) {
      const int col = pBase + wn * 64 + nj * 16 + row16;
      float* orow = Ob + (size_t)(cBase + wm * 128 + mi * 16 + quad * 4) * PP + col;
#pragma unroll
      for (int r = 0; r < 4; ++r)
        orow[(size_t)r * PP] = acc[mi][nj][r];
    }
}

// ---------------- scr8: S = (Qh+Ql)(Kh+Kl)^T -- 256x256 tile, 8-phase ----------------
// Same template as out8. LDS row = 128B packing [hi (chunks 0-3) | lo (chunks 4-7)]
// of one k-tile (BK=32 cols x 2B = 64B per tensor). K=256 -> 8 k-tiles, 3 iters+peel.
__global__ __launch_bounds__(512, 2) void scr8(
    const unsigned short* __restrict__ Qh_, const unsigned short* __restrict__ Ql_,
    const unsigned short* __restrict__ Kh_, const unsigned short* __restrict__ Kl_,
    float* __restrict__ S_) {
  const size_t z = blockIdx.z;
  const unsigned short* __restrict__ Qh = Qh_ + z * (size_t)PP * DD;
  const unsigned short* __restrict__ Ql = Ql_ + z * (size_t)PP * DD;
  const unsigned short* __restrict__ Kh = Kh_ + z * (size_t)PP * DD;
  const unsigned short* __restrict__ Kl = Kl_ + z * (size_t)PP * DD;
  float* __restrict__ S = S_ + z * (size_t)PP * PP;

  const int kBase = blockIdx.x * 256;   // N (key columns)
  const int pBase = blockIdx.y * 256;   // M (query rows)
  const int tid = threadIdx.x;
  const int wave = tid >> 6, lane = tid & 63;
  const int wm = wave >> 2;             // 0..1 (M)
  const int wn = wave & 3;              // 0..3 (N)
  const int wnh = wn >> 1, wnl = wn & 1;
  const int row16 = lane & 15, quad = lane >> 4;

  __shared__ __align__(16) char Lds[131072];

  const int swz = (row16 & 7) << 4;
  const int cx0 = ((quad) << 4) ^ swz;
  const int cx1 = ((4 + quad) << 4) ^ swz;

  const int stRow0 = (wave * 2 + 0) * 8 + (lane >> 3);
  const int stRow1 = (wave * 2 + 1) * 8 + (lane >> 3);
  const int cc   = (lane & 7) ^ (lane >> 3);
  const int ccB  = (cc & 3) * 16;            // byte within the tensor's k-slice
  const char* tQ = (const char*)((cc >> 2) ? Ql : Qh);
  const char* tK = (const char*)((cc >> 2) ? Kl : Kh);
  char* ldsSt0 = Lds + (wave * 2 + 0) * 1024;
  char* ldsSt1 = Lds + (wave * 2 + 1) * 1024;

  auto STG = [&](int ldsOff, const char* tbase, int rowBase, int tkB) {
    const char* g0 = tbase + (size_t)(rowBase + stRow0) * 512 + tkB + ccB;
    const char* g1 = tbase + (size_t)(rowBase + stRow1) * 512 + tkB + ccB;
    GLL(g0, ldsSt0 + ldsOff);
    GLL(g1, ldsSt1 + ldsOff);
  };

  f32x4 acc[8][4];
#pragma unroll
  for (int i = 0; i < 8; ++i)
#pragma unroll
    for (int j = 0; j < 4; ++j) acc[i][j] = (f32x4){0.f, 0.f, 0.f, 0.f};

  bf16x8 aR[4][2], bLo[2][2], bHi[2][2];

  // ---- prologue: tile0 B+A into dbuf0, tile1 B-halves into dbuf1 ----
  STG(BOFF(0, 0), tK, kBase + 0,   0);
  STG(BOFF(0, 1), tK, kBase + 128, 0);
  STG(AOFF(0, 0), tQ, pBase + 0,   0);
  STG(AOFF(0, 1), tQ, pBase + 128, 0);
  STG(BOFF(1, 0), tK, kBase + 0,   64);
  STG(BOFF(1, 1), tK, kBase + 128, 64);
  asm volatile("s_waitcnt vmcnt(4)" ::: "memory");
  __builtin_amdgcn_s_barrier();

#pragma unroll 1
  for (int i = 0; i < 3; ++i) {
    const int t = 2 * i;
    const int gk1 = (t + 1) * 64, gk2 = (t + 2) * 64, gk3 = (t + 3) * 64;
    PH_READ_A(0, 0); PH_READ_B(0, 0, bLo);
    STG(AOFF(1, 0), tQ, pBase + 0, gk1);
    BAR_MID(); PH_MFMA3(0, 0, bLo); BAR_END();
    PH_READ_B(0, 1, bHi);
    STG(AOFF(1, 1), tQ, pBase + 128, gk1);
    BAR_MID(); PH_MFMA3(0, 1, bHi); BAR_END();
    PH_READ_A(0, 1);
    STG(BOFF(0, 0), tK, kBase + 0, gk2);
    BAR_MID(); PH_MFMA3(1, 0, bLo); BAR_END();
    STG(BOFF(0, 1), tK, kBase + 128, gk2);
    BAR_MID(); PH_MFMA3(1, 1, bHi);
    asm volatile("s_waitcnt vmcnt(4)" ::: "memory");
    BAR_END();
    PH_READ_A(1, 0); PH_READ_B(1, 0, bLo);
    STG(AOFF(0, 0), tQ, pBase + 0, gk2);
    BAR_MID(); PH_MFMA3(0, 0, bLo); BAR_END();
    PH_READ_B(1, 1, bHi);
    STG(AOFF(0, 1), tQ, pBase + 128, gk2);
    BAR_MID(); PH_MFMA3(0, 1, bHi); BAR_END();
    PH_READ_A(1, 1);
    STG(BOFF(1, 0), tK, kBase + 0, gk3);
    BAR_MID(); PH_MFMA3(1, 0, bLo); BAR_END();
    STG(BOFF(1, 1), tK, kBase + 128, gk3);
    BAR_MID(); PH_MFMA3(1, 1, bHi);
    asm volatile("s_waitcnt vmcnt(4)" ::: "memory");
    BAR_END();
  }

  // ---- peeled final iter (k-tiles 6, 7) ----
  {
    const int gk1 = 7 * 64;
    PH_READ_A(0, 0); PH_READ_B(0, 0, bLo);
    STG(AOFF(1, 0), tQ, pBase + 0, gk1);
    BAR_MID(); PH_MFMA3(0, 0, bLo); BAR_END();
    PH_READ_B(0, 1, bHi);
    STG(AOFF(1, 1), tQ, pBase + 128, gk1);
    BAR_MID(); PH_MFMA3(0, 1, bHi); BAR_END();
    PH_READ_A(0, 1);
    BAR_MID(); PH_MFMA3(1, 0, bLo); BAR_END();
    BAR_MID(); PH_MFMA3(1, 1, bHi);
    asm volatile("s_waitcnt vmcnt(0)" ::: "memory");
    BAR_END();
    PH_READ_A(1, 0); PH_READ_B(1, 0, bLo);
    BAR_MID(); PH_MFMA3(0, 0, bLo); BAR_END();
    PH_READ_B(1, 1, bHi);
    BAR_MID(); PH_MFMA3(0, 1, bHi); BAR_END();
    PH_READ_A(1, 1);
    BAR_MID(); PH_MFMA3(1, 0, bLo); BAR_END();
    BAR_MID(); PH_MFMA3(1, 1, bHi);
  }

  // ---- epilogue: store S fp32 ----
#pragma unroll
  for (int mi = 0; mi < 8; ++mi)
#pragma unroll
    for (int nj = 0; nj < 4; ++nj) {
      const int kcol = kBase + wn * 64 + nj * 16 + row16;
      float* orow = S + (size_t)(pBase + wm * 128 + mi * 16 + quad * 4) * PP + kcol;
#pragma unroll
      for (int r = 0; r < 4; ++r)
        orow[(size_t)r * PP] = acc[mi][nj][r];
    }
}

extern "C" void kernel_launch(void* const* d_in, const int* in_sizes, int n_in,
                              void* d_out, int out_size, void* d_ws, size_t ws_size,
                              hipStream_t stream) {
  const float* Xq   = (const float*)d_in[0];
  const float* Xp   = (const float*)d_in[1];
  const float* Wg   = (const float*)d_in[2];
  const float* bias = (const float*)d_in[3];
  float* out = (float*)d_out;

  char* w = (char*)d_ws;
  const size_t MB = 1024 * 1024;
  const size_t CHPP = (size_t)CH * PP;

  if (ws_size >= 354 * MB) {
    // ---- fully batched path: 5 launches, 353 MB ----
    // Wf 1MB @0 | Qh/Ql/Kh/Kl 4x8MB @1..33 | Vbf 64MB @33 | S 256MB @97
    _Float16* Wf       = (_Float16*)w;
    unsigned short* Qh = (unsigned short*)(w + 1 * MB);
    unsigned short* Ql = (unsigned short*)(w + 9 * MB);
    unsigned short* Kh = (unsigned short*)(w + 17 * MB);
    unsigned short* Kl = (unsigned short*)(w + 25 * MB);
    unsigned short* Vbf = (unsigned short*)(w + 33 * MB);
    float* S           = (float*)(w + 97 * MB);

    prep_w<<<512, 256, 0, stream>>>(Wg, Wf);
    projX<<<dim3(PP / 64, 1, 2 * BATCH), 256, 0, stream>>>(
        Xq, Xp, Wf, bias, Qh, Ql, Kh, Kl, Vbf, 0, 0);
    scr8<<<dim3(PP / 256, PP / 256, BATCH), 512, 0, stream>>>(Qh, Ql, Kh, Kl, S);
    softmax8<<<dim3(PP, BATCH), 256, 0, stream>>>(S);
    out8<<<dim3(PP / 256, CH / 256, BATCH), 512, 0, stream>>>(
        Vbf, (unsigned short*)S, out);
  } else {
    // ---- legacy 89MB per-batch path ----
    // Wf 1MB @0 | Qh/Ql/Kh/Kl 4x2MB @1..9 | Vbf 16MB @9 | S 64MB @25
    _Float16* Wf       = (_Float16*)w;
    unsigned short* Qh = (unsigned short*)(w + 1 * MB);
    unsigned short* Ql = (unsigned short*)(w + 3 * MB);
    unsigned short* Kh = (unsigned short*)(w + 5 * MB);
    unsigned short* Kl = (unsigned short*)(w + 7 * MB);
    unsigned short* Vbf = (unsigned short*)(w + 9 * MB);
    float* S           = (float*)(w + 25 * MB);

    prep_w<<<512, 256, 0, stream>>>(Wg, Wf);
    for (int b = 0; b < BATCH; ++b) {
      projX<<<dim3(PP / 64, 1, 2), 256, 0, stream>>>(
          Xq, Xp, Wf, bias, Qh, Ql, Kh, Kl, Vbf, 2 * b, 1);
      scr8<<<dim3(PP / 256, PP / 256, 1), 512, 0, stream>>>(Qh, Ql, Kh, Kl, S);
      softmax8<<<dim3(PP, 1), 256, 0, stream>>>(S);
      out8<<<dim3(PP / 256, CH / 256, 1), 512, 0, stream>>>(
          Vbf, (unsigned short*)S, out + (size_t)b * CHPP);
    }
  }
}